// Round 12
// baseline (2126.423 us; speedup 1.0000x reference)
//
#include <hip/hip_runtime.h>

// GINEEncoderBlock — round 14: edge GEMM retiled for OCCUPANCY, launcher
// reverted to the proven serial R11 structure (co-launch 0-for-3: R10 tail
// -fuse, R12 4-deep, R13 gather-overlap all regressed; each kernel here
// wants the whole machine). Edge GEMM was 2 waves/SIMD (92 VGPR + 64 AGPR
// = 156 unified > 128 boundary) -> both pipes stall on es HBM latency.
// Retile 64x256 block as 8 waves x (32x64): acc 32 AGPR, no cross-kc W
// prefetch (L2-hot, TLP hides), plane-split A staging (pf 8 VGPR) ->
// ~80-95 VGPR + 32 AGPR <= 128 unified; __launch_bounds__(512,4) pins 4
// waves/SIMD = 50% occupancy (2x). Same blocks, same W traffic, same
// proven barrier/hazard structure.

#define D 256
#define BN_EPS 1e-5f

typedef __attribute__((ext_vector_type(8))) short bf16x8;
typedef __attribute__((ext_vector_type(8))) ushort u16x8;
typedef __attribute__((ext_vector_type(4))) float f32x4;

__device__ __forceinline__ ushort bf16h(float f) {
    uint u = __float_as_uint(f);
    return (ushort)((u + 0x7FFFu + ((u >> 16) & 1u)) >> 16);
}
__device__ __forceinline__ float bf16f(ushort h) {
    return __uint_as_float(((uint)h) << 16);
}

// truncation split: h = top16(f), l = top16(f - h); h+l ~ f to ~2^-16 rel.
__device__ __forceinline__ void split2(float f, ushort& h, ushort& l) {
    uint u = __float_as_uint(f);
    h = (ushort)(u >> 16);
    float r = f - __uint_as_float(u & 0xFFFF0000u);
    l = (ushort)(__float_as_uint(r) >> 16);
}

// ------------------------------------------------------------- CSR build ----
__global__ __launch_bounds__(256) void hist_kernel(
    const int* __restrict__ dst, int* __restrict__ cnt, int E)
{
    int i = blockIdx.x * 256 + threadIdx.x;
    if (i < E) atomicAdd(&cnt[dst[i]], 1);
}

__global__ __launch_bounds__(256) void scan_kernel(
    const int* __restrict__ cnt, int* __restrict__ row_ptr, int N)
{
    __shared__ int buf[256];
    __shared__ int carry_s;
    if (threadIdx.x == 0) { carry_s = 0; row_ptr[0] = 0; }
    __syncthreads();
    for (int base = 0; base < N; base += 256) {
        int i = base + threadIdx.x;
        int v = (i < N) ? cnt[i] : 0;
        buf[threadIdx.x] = v;
        __syncthreads();
#pragma unroll
        for (int off = 1; off < 256; off <<= 1) {
            int t = (threadIdx.x >= off) ? buf[threadIdx.x - off] : 0;
            __syncthreads();
            buf[threadIdx.x] += t;
            __syncthreads();
        }
        int inc = buf[threadIdx.x] + carry_s;
        if (i < N) row_ptr[i + 1] = inc;
        __syncthreads();
        if (threadIdx.x == 255) carry_s = inc;
        __syncthreads();
    }
}

__global__ __launch_bounds__(256) void fill_kernel(
    const int* __restrict__ dst, const int* __restrict__ src,
    const int* __restrict__ row_ptr, int* __restrict__ fillc,
    int* __restrict__ edge_idx, int* __restrict__ src_sorted, int E)
{
    int i = blockIdx.x * 256 + threadIdx.x;
    if (i < E) {
        int d = dst[i];
        int pos = atomicAdd(&fillc[d], 1);
        int slot = row_ptr[d] + pos;
        edge_idx[slot] = i;
        src_sorted[slot] = src[i];
    }
}

// ------------------------------------------------------- gather (layer 0) ----
__global__ __launch_bounds__(256) void gather_l0(
    const float* __restrict__ x, const float* __restrict__ e32,
    const int* __restrict__ src, const int* __restrict__ row_ptr,
    const int* __restrict__ edge_idx, float* __restrict__ aggr, int N)
{
    int node = blockIdx.x * 4 + (threadIdx.x >> 6);
    if (node >= N) return;
    int lane = threadIdx.x & 63;
    int beg = row_ptr[node], end = row_ptr[node + 1];
    float4 acc = make_float4(0.f, 0.f, 0.f, 0.f);
    for (int j = beg; j < end; ++j) {
        int ed = edge_idx[j];
        int s = src[ed];
        float4 ev = ((const float4*)(e32 + (size_t)ed * D))[lane];
        float4 xv = ((const float4*)(x + (size_t)s * D))[lane];
        acc.x += fmaxf(ev.x + xv.x, 0.f);
        acc.y += fmaxf(ev.y + xv.y, 0.f);
        acc.z += fmaxf(ev.z + xv.z, 0.f);
        acc.w += fmaxf(ev.w + xv.w, 0.f);
    }
    ((float4*)(aggr + (size_t)node * D))[lane] = acc;
}

// ------------------------------------------------- gather (sorted, BN-x) ----
__global__ __launch_bounds__(256) void gather_sorted(
    const float* __restrict__ x, const ushort* __restrict__ es,
    const int* __restrict__ src_sorted, const int* __restrict__ row_ptr,
    const float* __restrict__ stats, const float* __restrict__ gamma,
    const float* __restrict__ beta, float* __restrict__ aggr, int N)
{
    __shared__ float ssc[256], ssf[256];
    {
        int c = threadIdx.x;
        float inv_n = 1.f / (float)N;
        float mean = stats[c] * inv_n;
        float var  = stats[D + c] * inv_n - mean * mean;
        float sc = gamma[c] * rsqrtf(var + BN_EPS);
        ssc[c] = sc;
        ssf[c] = beta[c] - mean * sc;
    }
    __syncthreads();
    int node = blockIdx.x * 4 + (threadIdx.x >> 6);
    if (node >= N) return;
    int lane = threadIdx.x & 63;
    float4 sc4 = *(const float4*)&ssc[lane * 4];
    float4 sh4 = *(const float4*)&ssf[lane * 4];
    int beg = row_ptr[node], end = row_ptr[node + 1];
    float4 acc = make_float4(0.f, 0.f, 0.f, 0.f);
    for (int j = beg; j < end; ++j) {
        int s = src_sorted[j];
        const ushort* er = es + (size_t)j * 512;
        ushort4 hv = *(const ushort4*)(er + lane * 4);
        ushort4 lv = *(const ushort4*)(er + 256 + lane * 4);
        float4 xv = ((const float4*)(x + (size_t)s * D))[lane];
        float4 ev;
        ev.x = bf16f(hv.x) + bf16f(lv.x);
        ev.y = bf16f(hv.y) + bf16f(lv.y);
        ev.z = bf16f(hv.z) + bf16f(lv.z);
        ev.w = bf16f(hv.w) + bf16f(lv.w);
        xv.x = xv.x * sc4.x + sh4.x;
        xv.y = xv.y * sc4.y + sh4.y;
        xv.z = xv.z * sc4.z + sh4.z;
        xv.w = xv.w * sc4.w + sh4.w;
        acc.x += fmaxf(ev.x + xv.x, 0.f);
        acc.y += fmaxf(ev.y + xv.y, 0.f);
        acc.z += fmaxf(ev.z + xv.z, 0.f);
        acc.w += fmaxf(ev.w + xv.w, 0.f);
    }
    ((float4*)(aggr + (size_t)node * D))[lane] = acc;
}

// ------------------------------------------- W -> K-chunk-major bf16 hi/lo --
__global__ __launch_bounds__(256) void wconv_kernel(
    const float* __restrict__ W, ushort* __restrict__ WTh,
    ushort* __restrict__ WTl)
{
    int bk = blockIdx.x;            // layer*D + k
    int col = threadIdx.x;
    int layer = bk >> 8, k = bk & 255;
    float v = W[(size_t)bk * D + col];
    ushort h = bf16h(v);
    ushort lo = bf16h(v - bf16f(h));
    size_t o = (((size_t)layer * 8 + (k >> 5)) * 256 + col) * 32 + (k & 31);
    WTh[o] = h;
    WTl[o] = lo;
}

// ----------------------------------------------------- MFMA edge GEMM -------
// 64 rows x 256 cols per block, 512 threads = 8 waves of (32 rows x 64
// cols): wr = wave>>2 row-group, wc = wave&3 col-group. acc 2x4 frags =
// 32 AGPR. A 2-deep prefetch (plane-split staging: each thread owns one
// plane -> pf is 8 VGPR); W loaded per K-step, no cross-kc prefetch.
// One barrier per K-step; LDS = A dbuf (20.5KB) union Tr (34.8KB).
// In-place safe (sole reader+writer of its 64 rows).
template<int MODE>
__global__ __launch_bounds__(512, 4) void gemm_edge_mfma(
    const float* __restrict__ e32, const int* __restrict__ edge_idx,
    const ushort* __restrict__ esin, const ushort* __restrict__ WTh,
    const ushort* __restrict__ WTl, const float* __restrict__ bias,
    ushort* __restrict__ esout, int rows)
{
    __shared__ char smem[34816];
    ushort* AhB = (ushort*)smem;              // [2][64][40] = 10240B
    ushort* AlB = (ushort*)(smem + 10240);    // [2][64][40]
    float*  TrB = (float*)smem;               // [8][16][68] = 34816B (reuse)
#define AH(b, r, c) AhB[(b) * 2560 + (r) * 40 + (c)]
#define AL(b, r, c) AlB[(b) * 2560 + (r) * 40 + (c)]
#define TR(w, r, c) TrB[(w) * 1088 + (r) * 68 + (c)]

    const int tid  = threadIdx.x;
    const int lane = tid & 63;
    const int wave = tid >> 6;       // 0..7
    const int wr   = wave >> 2;      // row-group: rows wr*32..+31
    const int wc   = wave & 3;       // col-group: cols wc*64..+63
    const int m0   = blockIdx.x * 64;
    const int l15  = lane & 15;
    const int l4   = lane >> 4;
    const int wcol = wc * 64;

    f32x4 acc[2][4];
#pragma unroll
    for (int m = 0; m < 2; ++m)
#pragma unroll
        for (int n = 0; n < 4; ++n) acc[m][n] = (f32x4){0.f, 0.f, 0.f, 0.f};

    // ---- staging maps ----
    // MODE 1: 512 thr = 64 rows x 2 planes x 4 sectors(8 elems). Each
    // thread: one u16x8 load + one ds_write_b128 per K-chunk.
    // MODE 0: 512 thr = 64 rows x 8 sectors(4 fp32). float4 load, cvt,
    // two ds_write_b64.
    const int srow1 = tid >> 3;          // MODE1 row (0..63)
    const int spl   = (tid >> 2) & 1;    // MODE1 plane (0=hi,1=lo)
    const int sec8  = tid & 3;           // MODE1 8-elem sector
    const int srow0 = tid >> 3;          // MODE0 row
    const int sec4  = tid & 7;           // MODE0 4-elem sector
    const int sgr   = m0 + (MODE == 0 ? srow0 : srow1);
    const bool svalid = (sgr < rows);

    u16x8  ph[2] = {};                   // MODE1 prefetch (one plane)
    float4 pf[2] = {};                   // MODE0 prefetch
    bf16x8 bh[4], bl[4];

    const float*  a32 = nullptr;
    const ushort* ahi = nullptr;
    if (MODE == 0) {
        int erow = svalid ? edge_idx[sgr] : 0;
        a32 = e32 + (size_t)erow * D + sec4 * 4;
    } else {
        ahi = esin + (size_t)sgr * 512 + spl * 256 + sec8 * 8;
    }

    // ---- prologue: A chunks 0,1 -> reg sets; stage set0 -> buf0 ----
    if (svalid) {
        if (MODE == 0) {
            pf[0] = *(const float4*)a32;
            pf[1] = *(const float4*)(a32 + 32);
        } else {
            ph[0] = *(const u16x8*)ahi;
            ph[1] = *(const u16x8*)(ahi + 32);
        }
    }
    if (MODE == 0) {
        ushort4 h4, l4v;
        split2(pf[0].x, h4.x, l4v.x);
        split2(pf[0].y, h4.y, l4v.y);
        split2(pf[0].z, h4.z, l4v.z);
        split2(pf[0].w, h4.w, l4v.w);
        *(ushort4*)&AH(0, srow0, sec4 * 4) = h4;
        *(ushort4*)&AL(0, srow0, sec4 * 4) = l4v;
    } else {
        ushort* dst = spl ? &AL(0, srow1, sec8 * 8) : &AH(0, srow1, sec8 * 8);
        *(u16x8*)dst = ph[0];
    }
    __syncthreads();

    // ---- K loop: 8 chunks of 32; A 2-deep prefetch, W per-kc ----
#pragma unroll
    for (int kc = 0; kc < 8; ++kc) {
        const int cur = kc & 1;
        if (kc < 6 && svalid) {            // issue A(kc+2) into set kc&1
            if (MODE == 0)
                pf[kc & 1] = *(const float4*)(a32 + (kc + 2) * 32);
            else
                ph[kc & 1] = *(const u16x8*)(ahi + (kc + 2) * 32);
        }
        // W frags for this kc (L2-hot; TLP hides the latency)
#pragma unroll
        for (int n = 0; n < 4; ++n) {
            size_t o = ((size_t)kc * 256 + wcol + n * 16 + l15) * 32 + l4 * 8;
            bh[n] = *(const bf16x8*)(WTh + o);
            bl[n] = *(const bf16x8*)(WTl + o);
        }
        bf16x8 ah[2], al[2];
#pragma unroll
        for (int m = 0; m < 2; ++m) {
            ah[m] = *(const bf16x8*)&AH(cur, wr * 32 + m * 16 + l15, l4 * 8);
            al[m] = *(const bf16x8*)&AL(cur, wr * 32 + m * 16 + l15, l4 * 8);
        }
#pragma unroll
        for (int m = 0; m < 2; ++m)
#pragma unroll
            for (int n = 0; n < 4; ++n) {
                acc[m][n] = __builtin_amdgcn_mfma_f32_16x16x32_bf16(
                    ah[m], bh[n], acc[m][n], 0, 0, 0);
                acc[m][n] = __builtin_amdgcn_mfma_f32_16x16x32_bf16(
                    ah[m], bl[n], acc[m][n], 0, 0, 0);
                acc[m][n] = __builtin_amdgcn_mfma_f32_16x16x32_bf16(
                    al[m], bh[n], acc[m][n], 0, 0, 0);
            }
        if (kc < 7) {                      // stage A(kc+1) -> other buffer
            const int ns = (kc + 1) & 1;
            if (MODE == 0) {
                ushort4 h4, l4v;
                split2(pf[ns].x, h4.x, l4v.x);
                split2(pf[ns].y, h4.y, l4v.y);
                split2(pf[ns].z, h4.z, l4v.z);
                split2(pf[ns].w, h4.w, l4v.w);
                *(ushort4*)&AH(cur ^ 1, srow0, sec4 * 4) = h4;
                *(ushort4*)&AL(cur ^ 1, srow0, sec4 * 4) = l4v;
            } else {
                ushort* dst = spl ? &AL(cur ^ 1, srow1, sec8 * 8)
                                  : &AH(cur ^ 1, srow1, sec8 * 8);
                *(u16x8*)dst = ph[ns];
            }
        }
        __syncthreads();
    }

    // ---- epilogue: bias+relu -> per-wave LDS transpose -> es stores ----
#pragma unroll
    for (int h = 0; h < 2; ++h) {
        __syncthreads();
        {
            const int m = h;
#pragma unroll
            for (int n = 0; n < 4; ++n) {
                float bv = bias[wcol + n * 16 + l15];
#pragma unroll
                for (int r = 0; r < 4; ++r)
                    TR(wave, l4 * 4 + r, n * 16 + l15) =
                        fmaxf(acc[m][n][r] + bv, 0.f);
            }
        }
        __syncthreads();
#pragma unroll
        for (int p = 0; p < 4; ++p) {
            int row  = p * 4 + l4;                       // 0..15
            int grow = m0 + wr * 32 + h * 16 + row;
            if (grow < rows) {
                float4 v = *(const float4*)&TR(wave, row, l15 * 4);
                ushort4 h4, l4v;
                split2(v.x, h4.x, l4v.x);
                split2(v.y, h4.y, l4v.y);
                split2(v.z, h4.z, l4v.z);
                split2(v.w, h4.w, l4v.w);
                size_t off = (size_t)grow * 512 + wcol + l15 * 4;
                *(ushort4*)(esout + off) = h4;
                *(ushort4*)(esout + off + 256) = l4v;
            }
        }
    }
#undef AH
#undef AL
#undef TR
}

// ------------------------------------------------------------------- GEMM ----
// fp32 row-full GEMM for node convs (N=10k). BN_A: scale/shift inline in
// LDS from stats_in+gamma/beta. DO_STATS: column sum/sumsq into stats_out.
template<bool BN_A, bool ADD_INIT, bool DO_STATS>
__global__ __launch_bounds__(256) void gemm_rowfull(
    const float* A, const float* __restrict__ aggr,
    const float* __restrict__ W, const float* __restrict__ bias,
    const float* __restrict__ stats_in, const float* __restrict__ gamma,
    const float* __restrict__ beta, const float* __restrict__ init,
    float* out, float* __restrict__ stats_out, int rows)
{
    __shared__ float As[16][68];
    __shared__ float Bs[16][260];
    __shared__ float ssc[256], ssf[256];

    const int tid = threadIdx.x;
    const int m0 = blockIdx.x * 64;
    const int tx = tid & 15;
    const int ty = tid >> 4;

    const int arow = tid >> 2;
    const int ak4  = (tid & 3) << 2;
    const int bk   = tid >> 4;
    const int bn4  = (tid & 15) << 2;

    if (BN_A) {
        float inv_n = 1.f / (float)rows;
        float mean = stats_in[tid] * inv_n;
        float var  = stats_in[D + tid] * inv_n - mean * mean;
        float sc = gamma[tid] * rsqrtf(var + BN_EPS);
        ssc[tid] = sc;
        ssf[tid] = beta[tid] - mean * sc;
        __syncthreads();
    }

    float acc[4][16];
#pragma unroll
    for (int i = 0; i < 4; ++i)
#pragma unroll
        for (int j = 0; j < 16; ++j) acc[i][j] = 0.f;

    for (int k0 = 0; k0 < D; k0 += 16) {
        float4 av = make_float4(0.f, 0.f, 0.f, 0.f);
        int gr = m0 + arow;
        if (gr < rows) {
            av = *(const float4*)(A + (size_t)gr * D + k0 + ak4);
            if (BN_A) {
                float4 sc = *(const float4*)&ssc[k0 + ak4];
                float4 sh = *(const float4*)&ssf[k0 + ak4];
                av.x = av.x * sc.x + sh.x;
                av.y = av.y * sc.y + sh.y;
                av.z = av.z * sc.z + sh.z;
                av.w = av.w * sc.w + sh.w;
            }
            float4 g = *(const float4*)(aggr + (size_t)gr * D + k0 + ak4);
            av.x += g.x; av.y += g.y; av.z += g.z; av.w += g.w;
        }
        As[ak4 + 0][arow] = av.x;
        As[ak4 + 1][arow] = av.y;
        As[ak4 + 2][arow] = av.z;
        As[ak4 + 3][arow] = av.w;
#pragma unroll
        for (int c = 0; c < 4; ++c)
            *(float4*)&Bs[bk][c * 64 + bn4] =
                *(const float4*)(W + (size_t)(k0 + bk) * D + c * 64 + bn4);
        __syncthreads();
#pragma unroll
        for (int k = 0; k < 16; ++k) {
            float4 a4 = *(const float4*)&As[k][ty << 2];
            float a[4] = {a4.x, a4.y, a4.z, a4.w};
#pragma unroll
            for (int jc = 0; jc < 4; ++jc) {
                float4 b4 = *(const float4*)&Bs[k][(jc << 6) + (tx << 2)];
#pragma unroll
                for (int i = 0; i < 4; ++i) {
                    acc[i][jc * 4 + 0] += a[i] * b4.x;
                    acc[i][jc * 4 + 1] += a[i] * b4.y;
                    acc[i][jc * 4 + 2] += a[i] * b4.z;
                    acc[i][jc * 4 + 3] += a[i] * b4.w;
                }
            }
        }
        __syncthreads();
    }

    float4 s4[4], q4[4];
#pragma unroll
    for (int jc = 0; jc < 4; ++jc) {
        s4[jc] = make_float4(0.f, 0.f, 0.f, 0.f);
        q4[jc] = make_float4(0.f, 0.f, 0.f, 0.f);
    }
#pragma unroll
    for (int jc = 0; jc < 4; ++jc) {
        int col = (jc << 6) + (tx << 2);
        float4 bias4 = *(const float4*)(bias + col);
#pragma unroll
        for (int i = 0; i < 4; ++i) {
            int gr = m0 + (ty << 2) + i;
            if (gr < rows) {
                float4 o;
                o.x = fmaxf(acc[i][jc * 4 + 0] + bias4.x, 0.f);
                o.y = fmaxf(acc[i][jc * 4 + 1] + bias4.y, 0.f);
                o.z = fmaxf(acc[i][jc * 4 + 2] + bias4.z, 0.f);
                o.w = fmaxf(acc[i][jc * 4 + 3] + bias4.w, 0.f);
                if (ADD_INIT) {
                    float4 iv = *(const float4*)(init + (size_t)gr * D + col);
                    o.x += iv.x; o.y += iv.y; o.z += iv.z; o.w += iv.w;
                }
                if (DO_STATS) {
                    s4[jc].x += o.x; s4[jc].y += o.y;
                    s4[jc].z += o.z; s4[jc].w += o.w;
                    q4[jc].x += o.x * o.x; q4[jc].y += o.y * o.y;
                    q4[jc].z += o.z * o.z; q4[jc].w += o.w * o.w;
                }
                *(float4*)(out + (size_t)gr * D + col) = o;
            }
        }
    }

    if (DO_STATS) {
#pragma unroll
        for (int jc = 0; jc < 4; ++jc)
            *(float4*)&Bs[ty][(jc << 6) + (tx << 2)] = s4[jc];
        __syncthreads();
        {
            float s = 0.f;
#pragma unroll
            for (int t = 0; t < 16; ++t) s += Bs[t][tid];
            atomicAdd(&stats_out[tid], s);
        }
        __syncthreads();
#pragma unroll
        for (int jc = 0; jc < 4; ++jc)
            *(float4*)&Bs[ty][(jc << 6) + (tx << 2)] = q4[jc];
        __syncthreads();
        {
            float s = 0.f;
#pragma unroll
            for (int t = 0; t < 16; ++t) s += Bs[t][tid];
            atomicAdd(&stats_out[D + tid], s);
        }
    }
}

// ----------------------------------------------------------------- launch ----
extern "C" void kernel_launch(void* const* d_in, const int* in_sizes, int n_in,
                              void* d_out, int out_size, void* d_ws, size_t ws_size,
                              hipStream_t stream)
{
    const float* node_feat = (const float*)d_in[0];
    const float* e32       = (const float*)d_in[1];
    const int*   src       = (const int*)d_in[2];
    const int*   dst       = (const int*)d_in[3];
    const float* W_conv    = (const float*)d_in[4];
    const float* b_conv    = (const float*)d_in[5];
    const float* W_edge    = (const float*)d_in[6];
    const float* b_edge    = (const float*)d_in[7];
    const float* gamma     = (const float*)d_in[8];
    const float* beta      = (const float*)d_in[9];
    float*       out       = (float*)d_out;

    const int N = in_sizes[0] / D;
    const int E = in_sizes[2];
    const int L = in_sizes[5] / D;

    float* x          = (float*)d_ws;                  // N*D f32
    float* aggr       = x + (size_t)N * D;             // N*D f32
    float* stats      = aggr + (size_t)N * D;          // L*2*D (slots)
    int*   cnt        = (int*)(stats + (size_t)L * 2 * D); // N
    int*   row_ptr    = cnt + N;                       // N+1
    int*   fillc      = row_ptr + N + 1;               // N
    int*   edge_idx   = fillc + N;                     // E
    int*   src_sorted = edge_idx + E;                  // E
    uintptr_t pa      = ((uintptr_t)(src_sorted + E) + 63) & ~(uintptr_t)63;
    ushort* WTh       = (ushort*)pa;                   // L*D*D bf16 hi
    ushort* WTl       = WTh + (size_t)L * D * D;       // L*D*D bf16 lo
    ushort* es        = WTl + (size_t)L * D * D;       // E*512 (hi|lo rows)

    int nodeBlocks    = (N + 63) / 64;
    int edgeBlocks    = (E + 63) / 64;
    int gatherBlocks  = (N + 3) / 4;
    int eThreadBlocks = (E + 255) / 256;

    // ---- one-time: zero stats slots + CSR + W_edge K-chunk-major hi/lo ----
    hipMemsetAsync(cnt, 0, (size_t)N * sizeof(int), stream);
    hipMemsetAsync(fillc, 0, (size_t)N * sizeof(int), stream);
    hipMemsetAsync(stats, 0, (size_t)L * 2 * D * sizeof(float), stream);
    hist_kernel<<<eThreadBlocks, 256, 0, stream>>>(dst, cnt, E);
    scan_kernel<<<1, 256, 0, stream>>>(cnt, row_ptr, N);
    fill_kernel<<<eThreadBlocks, 256, 0, stream>>>(
        dst, src, row_ptr, fillc, edge_idx, src_sorted, E);
    wconv_kernel<<<L * D, 256, 0, stream>>>(W_edge, WTh, WTl);

    for (int i = 0; i < L; ++i) {
        if (i == 0) {
            gather_l0<<<gatherBlocks, 256, 0, stream>>>(
                node_feat, e32, src, row_ptr, edge_idx, aggr, N);
            gemm_rowfull<false, false, true><<<nodeBlocks, 256, 0, stream>>>(
                node_feat, aggr, W_conv, b_conv, nullptr, nullptr, nullptr,
                nullptr, x, stats, N);
        } else {
            const float* st = stats + (size_t)(i - 1) * 2 * D;
            gather_sorted<<<gatherBlocks, 256, 0, stream>>>(
                x, es, src_sorted, row_ptr, st, gamma + (size_t)(i - 1) * D,
                beta + (size_t)(i - 1) * D, aggr, N);
            gemm_rowfull<true, false, true><<<nodeBlocks, 256, 0, stream>>>(
                x, aggr, W_conv + (size_t)i * D * D, b_conv + (size_t)i * D,
                st, gamma + (size_t)(i - 1) * D, beta + (size_t)(i - 1) * D,
                nullptr, x, stats + (size_t)i * 2 * D, N);
        }
        if (i == 0)
            gemm_edge_mfma<0><<<edgeBlocks, 512, 0, stream>>>(
                e32, edge_idx, nullptr, WTh, WTl, b_edge, es, E);
        else
            gemm_edge_mfma<1><<<edgeBlocks, 512, 0, stream>>>(
                nullptr, nullptr, es, WTh + (size_t)i * D * D,
                WTl + (size_t)i * D * D, b_edge + (size_t)i * D, es, E);
    }

    // final conv: layer L-1 weights on (BN_3(x), gather(es_4)), + node_feat
    {
        const float* st = stats + (size_t)(L - 1) * 2 * D;
        gather_sorted<<<gatherBlocks, 256, 0, stream>>>(
            x, es, src_sorted, row_ptr, st, gamma + (size_t)(L - 1) * D,
            beta + (size_t)(L - 1) * D, aggr, N);
        gemm_rowfull<true, true, false><<<nodeBlocks, 256, 0, stream>>>(
            x, aggr, W_conv + (size_t)(L - 1) * D * D, b_conv + (size_t)(L - 1) * D,
            st, gamma + (size_t)(L - 1) * D, beta + (size_t)(L - 1) * D,
            node_feat, out, nullptr, N);
    }
}

// Round 13
// 1833.540 us; speedup vs baseline: 1.1597x; 1.1597x over previous
//
#include <hip/hip_runtime.h>

// GINEEncoderBlock — round 15: full revert to the proven R11 structure
// (1835us; R12 ILP / R13 overlap / R14 TLP all regressed the edge GEMM —
// its 64x64-wave 2-deep form is a measured local optimum) + ONE zero-risk
// change: manual 1-deep software pipelining in both gather kernels
// (issue iter j+1's index/es/x loads before computing iter j). The
// gathers (~450us total) run ~35-55% above their HBM floor on a
// dependent src->x load chain; pure scheduling, numerics identical.

#define D 256
#define BN_EPS 1e-5f

typedef __attribute__((ext_vector_type(8))) short bf16x8;
typedef __attribute__((ext_vector_type(8))) ushort u16x8;
typedef __attribute__((ext_vector_type(4))) float f32x4;

__device__ __forceinline__ ushort bf16h(float f) {
    uint u = __float_as_uint(f);
    return (ushort)((u + 0x7FFFu + ((u >> 16) & 1u)) >> 16);
}
__device__ __forceinline__ float bf16f(ushort h) {
    return __uint_as_float(((uint)h) << 16);
}

// truncation split: h = top16(f), l = top16(f - h); h+l ~ f to ~2^-16 rel.
__device__ __forceinline__ void split2(float f, ushort& h, ushort& l) {
    uint u = __float_as_uint(f);
    h = (ushort)(u >> 16);
    float r = f - __uint_as_float(u & 0xFFFF0000u);
    l = (ushort)(__float_as_uint(r) >> 16);
}

__device__ __forceinline__ void cvt_write8(const float4& x0, const float4& x1,
                                           ushort* dh, ushort* dl) {
    float f[8] = {x0.x, x0.y, x0.z, x0.w, x1.x, x1.y, x1.z, x1.w};
    u16x8 hv, lv;
#pragma unroll
    for (int j = 0; j < 8; ++j) {
        ushort h, l;
        split2(f[j], h, l);
        hv[j] = h; lv[j] = l;
    }
    *(u16x8*)dh = hv;
    *(u16x8*)dl = lv;
}

// ------------------------------------------------------------- CSR build ----
__global__ __launch_bounds__(256) void hist_kernel(
    const int* __restrict__ dst, int* __restrict__ cnt, int E)
{
    int i = blockIdx.x * 256 + threadIdx.x;
    if (i < E) atomicAdd(&cnt[dst[i]], 1);
}

__global__ __launch_bounds__(256) void scan_kernel(
    const int* __restrict__ cnt, int* __restrict__ row_ptr, int N)
{
    __shared__ int buf[256];
    __shared__ int carry_s;
    if (threadIdx.x == 0) { carry_s = 0; row_ptr[0] = 0; }
    __syncthreads();
    for (int base = 0; base < N; base += 256) {
        int i = base + threadIdx.x;
        int v = (i < N) ? cnt[i] : 0;
        buf[threadIdx.x] = v;
        __syncthreads();
#pragma unroll
        for (int off = 1; off < 256; off <<= 1) {
            int t = (threadIdx.x >= off) ? buf[threadIdx.x - off] : 0;
            __syncthreads();
            buf[threadIdx.x] += t;
            __syncthreads();
        }
        int inc = buf[threadIdx.x] + carry_s;
        if (i < N) row_ptr[i + 1] = inc;
        __syncthreads();
        if (threadIdx.x == 255) carry_s = inc;
        __syncthreads();
    }
}

__global__ __launch_bounds__(256) void fill_kernel(
    const int* __restrict__ dst, const int* __restrict__ src,
    const int* __restrict__ row_ptr, int* __restrict__ fillc,
    int* __restrict__ edge_idx, int* __restrict__ src_sorted, int E)
{
    int i = blockIdx.x * 256 + threadIdx.x;
    if (i < E) {
        int d = dst[i];
        int pos = atomicAdd(&fillc[d], 1);
        int slot = row_ptr[d] + pos;
        edge_idx[slot] = i;
        src_sorted[slot] = src[i];
    }
}

// ------------------------------------------------------- gather (layer 0) ----
// manual 1-deep pipeline: issue iter j+1's idx/e/x loads before compute(j).
__global__ __launch_bounds__(256) void gather_l0(
    const float* __restrict__ x, const float* __restrict__ e32,
    const int* __restrict__ src, const int* __restrict__ row_ptr,
    const int* __restrict__ edge_idx, float* __restrict__ aggr, int N)
{
    int node = blockIdx.x * 4 + (threadIdx.x >> 6);
    if (node >= N) return;
    int lane = threadIdx.x & 63;
    int beg = row_ptr[node], end = row_ptr[node + 1];
    float4 acc = make_float4(0.f, 0.f, 0.f, 0.f);
    if (beg < end) {
        int ed0 = edge_idx[beg];
        int s0  = src[ed0];
        float4 e0 = ((const float4*)(e32 + (size_t)ed0 * D))[lane];
        float4 x0 = ((const float4*)(x + (size_t)s0 * D))[lane];
        for (int j = beg + 1; j < end; ++j) {
            int ed1 = edge_idx[j];
            int s1  = src[ed1];
            float4 e1 = ((const float4*)(e32 + (size_t)ed1 * D))[lane];
            float4 x1 = ((const float4*)(x + (size_t)s1 * D))[lane];
            acc.x += fmaxf(e0.x + x0.x, 0.f);
            acc.y += fmaxf(e0.y + x0.y, 0.f);
            acc.z += fmaxf(e0.z + x0.z, 0.f);
            acc.w += fmaxf(e0.w + x0.w, 0.f);
            e0 = e1; x0 = x1;
        }
        acc.x += fmaxf(e0.x + x0.x, 0.f);
        acc.y += fmaxf(e0.y + x0.y, 0.f);
        acc.z += fmaxf(e0.z + x0.z, 0.f);
        acc.w += fmaxf(e0.w + x0.w, 0.f);
    }
    ((float4*)(aggr + (size_t)node * D))[lane] = acc;
}

// ------------------------------------------------- gather (sorted, BN-x) ----
// es sequential; src_sorted sequential; BN scale/shift inline in LDS.
// manual 1-deep pipeline on the src->x dependent chain.
__global__ __launch_bounds__(256) void gather_sorted(
    const float* __restrict__ x, const ushort* __restrict__ es,
    const int* __restrict__ src_sorted, const int* __restrict__ row_ptr,
    const float* __restrict__ stats, const float* __restrict__ gamma,
    const float* __restrict__ beta, float* __restrict__ aggr, int N)
{
    __shared__ float ssc[256], ssf[256];
    {
        int c = threadIdx.x;
        float inv_n = 1.f / (float)N;
        float mean = stats[c] * inv_n;
        float var  = stats[D + c] * inv_n - mean * mean;
        float sc = gamma[c] * rsqrtf(var + BN_EPS);
        ssc[c] = sc;
        ssf[c] = beta[c] - mean * sc;
    }
    __syncthreads();
    int node = blockIdx.x * 4 + (threadIdx.x >> 6);
    if (node >= N) return;
    int lane = threadIdx.x & 63;
    float4 sc4 = *(const float4*)&ssc[lane * 4];
    float4 sh4 = *(const float4*)&ssf[lane * 4];
    int beg = row_ptr[node], end = row_ptr[node + 1];
    float4 acc = make_float4(0.f, 0.f, 0.f, 0.f);
    if (beg < end) {
        int s0 = src_sorted[beg];
        const ushort* er0 = es + (size_t)beg * 512;
        ushort4 hv0 = *(const ushort4*)(er0 + lane * 4);
        ushort4 lv0 = *(const ushort4*)(er0 + 256 + lane * 4);
        float4  xv0 = ((const float4*)(x + (size_t)s0 * D))[lane];
        for (int j = beg + 1; j < end; ++j) {
            int s1 = src_sorted[j];
            const ushort* er1 = es + (size_t)j * 512;
            ushort4 hv1 = *(const ushort4*)(er1 + lane * 4);
            ushort4 lv1 = *(const ushort4*)(er1 + 256 + lane * 4);
            float4  xv1 = ((const float4*)(x + (size_t)s1 * D))[lane];
            float4 ev;
            ev.x = bf16f(hv0.x) + bf16f(lv0.x);
            ev.y = bf16f(hv0.y) + bf16f(lv0.y);
            ev.z = bf16f(hv0.z) + bf16f(lv0.z);
            ev.w = bf16f(hv0.w) + bf16f(lv0.w);
            acc.x += fmaxf(xv0.x * sc4.x + sh4.x + ev.x, 0.f);
            acc.y += fmaxf(xv0.y * sc4.y + sh4.y + ev.y, 0.f);
            acc.z += fmaxf(xv0.z * sc4.z + sh4.z + ev.z, 0.f);
            acc.w += fmaxf(xv0.w * sc4.w + sh4.w + ev.w, 0.f);
            hv0 = hv1; lv0 = lv1; xv0 = xv1;
        }
        float4 ev;
        ev.x = bf16f(hv0.x) + bf16f(lv0.x);
        ev.y = bf16f(hv0.y) + bf16f(lv0.y);
        ev.z = bf16f(hv0.z) + bf16f(lv0.z);
        ev.w = bf16f(hv0.w) + bf16f(lv0.w);
        acc.x += fmaxf(xv0.x * sc4.x + sh4.x + ev.x, 0.f);
        acc.y += fmaxf(xv0.y * sc4.y + sh4.y + ev.y, 0.f);
        acc.z += fmaxf(xv0.z * sc4.z + sh4.z + ev.z, 0.f);
        acc.w += fmaxf(xv0.w * sc4.w + sh4.w + ev.w, 0.f);
    }
    ((float4*)(aggr + (size_t)node * D))[lane] = acc;
}

// ------------------------------------------- W -> K-chunk-major bf16 hi/lo --
__global__ __launch_bounds__(256) void wconv_kernel(
    const float* __restrict__ W, ushort* __restrict__ WTh,
    ushort* __restrict__ WTl)
{
    int bk = blockIdx.x;            // layer*D + k
    int col = threadIdx.x;
    int layer = bk >> 8, k = bk & 255;
    float v = W[(size_t)bk * D + col];
    ushort h = bf16h(v);
    ushort lo = bf16h(v - bf16f(h));
    size_t o = (((size_t)layer * 8 + (k >> 5)) * 256 + col) * 32 + (k & 31);
    WTh[o] = h;
    WTl[o] = lo;
}

// ----------------------------------------------------- MFMA edge GEMM -------
// PROVEN R11 version, byte-identical: 64x256/block, 4 waves (256 thr),
// 4x4 16x16x32 frags, hi/lo 3-MFMA; MODE 0 = permuted fp32 input (cvt
// staging), MODE 1 = es linear in-place; A 2-deep / W 1-deep prefetch,
// one barrier per K-step; LDS union 34.8KB; epilogue Tr transpose ->
// es row stores [256 hi][256 lo].
template<int MODE>
__global__ __launch_bounds__(256) void gemm_edge_mfma(
    const float* __restrict__ e32, const int* __restrict__ edge_idx,
    const ushort* __restrict__ esin, const ushort* __restrict__ WTh,
    const ushort* __restrict__ WTl, const float* __restrict__ bias,
    ushort* __restrict__ es, int rows)
{
    __shared__ char smem[34816];
    ushort* AhB = (ushort*)smem;              // [2][64][40]
    ushort* AlB = (ushort*)(smem + 10240);    // [2][64][40]
    float*  TrB = (float*)smem;               // [4][32][68] (epilogue reuse)
#define AH(b, r, c) AhB[(b) * 2560 + (r) * 40 + (c)]
#define AL(b, r, c) AlB[(b) * 2560 + (r) * 40 + (c)]
#define TR(w, r, c) TrB[(w) * 2176 + (r) * 68 + (c)]

    const int tid  = threadIdx.x;
    const int lane = tid & 63;
    const int wave = tid >> 6;
    const int m0   = blockIdx.x * 64;
    const int l15  = lane & 15;
    const int l4   = lane >> 4;
    const int wcol = wave * 64;

    const int srow = tid >> 2;    // 0..63
    const int ssec = tid & 3;     // 8-elem sector
    const int sgr  = m0 + srow;
    const bool svalid = (sgr < rows);

    f32x4 acc[4][4];
#pragma unroll
    for (int m = 0; m < 4; ++m)
#pragma unroll
        for (int n = 0; n < 4; ++n) acc[m][n] = (f32x4){0.f, 0.f, 0.f, 0.f};

    float4 pf0[2] = {}, pf1[2] = {};      // MODE0 prefetch sets
    u16x8  ph[2] = {}, pl[2] = {};        // MODE1 prefetch sets
    bf16x8 bh[4], bl[4], bhn[4], bln[4];

    const float*  a32 = nullptr;
    const ushort* ahi = nullptr;
    if (MODE == 0) {
        int erow = svalid ? edge_idx[sgr] : 0;
        a32 = e32 + (size_t)erow * D + ssec * 8;
    } else {
        ahi = esin + (size_t)sgr * 512 + ssec * 8;   // lo at +256
    }

    // ---- prologue: A chunks 0,1 -> reg sets 0,1; W chunk 0 -> regs ----
    if (svalid) {
        if (MODE == 0) {
            pf0[0] = *(const float4*)a32;        pf1[0] = *(const float4*)(a32 + 4);
            pf0[1] = *(const float4*)(a32 + 32); pf1[1] = *(const float4*)(a32 + 36);
        } else {
            ph[0] = *(const u16x8*)ahi;          pl[0] = *(const u16x8*)(ahi + 256);
            ph[1] = *(const u16x8*)(ahi + 32);   pl[1] = *(const u16x8*)(ahi + 288);
        }
    }
#pragma unroll
    for (int n = 0; n < 4; ++n) {
        size_t o = ((size_t)(wcol + n * 16 + l15)) * 32 + l4 * 8;
        bh[n] = *(const bf16x8*)(WTh + o);
        bl[n] = *(const bf16x8*)(WTl + o);
    }
    if (MODE == 0) {
        cvt_write8(pf0[0], pf1[0], &AH(0, srow, ssec * 8), &AL(0, srow, ssec * 8));
    } else {
        *(u16x8*)&AH(0, srow, ssec * 8) = ph[0];
        *(u16x8*)&AL(0, srow, ssec * 8) = pl[0];
    }
    __syncthreads();

    // ---- K loop: 8 chunks of 32; A 2-deep, W 1-deep prefetch ----
#pragma unroll
    for (int kc = 0; kc < 8; ++kc) {
        const int cur = kc & 1;
        if (kc < 6 && svalid) {            // issue A(kc+2) into set kc&1
            if (MODE == 0) {
                const float* p = a32 + (kc + 2) * 32;
                pf0[kc & 1] = *(const float4*)p;
                pf1[kc & 1] = *(const float4*)(p + 4);
            } else {
                ph[kc & 1] = *(const u16x8*)(ahi + (kc + 2) * 32);
                pl[kc & 1] = *(const u16x8*)(ahi + 256 + (kc + 2) * 32);
            }
        }
        bf16x8 ah[4], al[4];
#pragma unroll
        for (int m = 0; m < 4; ++m) {
            ah[m] = *(const bf16x8*)&AH(cur, m * 16 + l15, l4 * 8);
            al[m] = *(const bf16x8*)&AL(cur, m * 16 + l15, l4 * 8);
        }
        if (kc < 7) {                      // issue W(kc+1)
#pragma unroll
            for (int n = 0; n < 4; ++n) {
                size_t o = ((size_t)(kc + 1) * 256 + wcol + n * 16 + l15) * 32 + l4 * 8;
                bhn[n] = *(const bf16x8*)(WTh + o);
                bln[n] = *(const bf16x8*)(WTl + o);
            }
        }
#pragma unroll
        for (int m = 0; m < 4; ++m)
#pragma unroll
            for (int n = 0; n < 4; ++n) {
                acc[m][n] = __builtin_amdgcn_mfma_f32_16x16x32_bf16(
                    ah[m], bh[n], acc[m][n], 0, 0, 0);
                acc[m][n] = __builtin_amdgcn_mfma_f32_16x16x32_bf16(
                    ah[m], bl[n], acc[m][n], 0, 0, 0);
                acc[m][n] = __builtin_amdgcn_mfma_f32_16x16x32_bf16(
                    al[m], bh[n], acc[m][n], 0, 0, 0);
            }
        if (kc < 7) {                      // stage A(kc+1) -> other buffer
            const int ns = (kc + 1) & 1;
            if (MODE == 0) {
                cvt_write8(pf0[ns], pf1[ns],
                           &AH(cur ^ 1, srow, ssec * 8), &AL(cur ^ 1, srow, ssec * 8));
            } else {
                *(u16x8*)&AH(cur ^ 1, srow, ssec * 8) = ph[ns];
                *(u16x8*)&AL(cur ^ 1, srow, ssec * 8) = pl[ns];
            }
#pragma unroll
            for (int n = 0; n < 4; ++n) { bh[n] = bhn[n]; bl[n] = bln[n]; }
        }
        __syncthreads();
    }

    // ---- epilogue: bias+relu -> LDS transpose -> es row stores ----
#pragma unroll
    for (int h = 0; h < 2; ++h) {
        __syncthreads();
#pragma unroll
        for (int mm = 0; mm < 2; ++mm) {
            int m = h * 2 + mm;
#pragma unroll
            for (int n = 0; n < 4; ++n) {
                float bv = bias[wcol + n * 16 + l15];
#pragma unroll
                for (int r = 0; r < 4; ++r)
                    TR(wave, mm * 16 + l4 * 4 + r, n * 16 + l15) =
                        fmaxf(acc[m][n][r] + bv, 0.f);
            }
        }
        __syncthreads();
#pragma unroll
        for (int p = 0; p < 8; ++p) {
            int row  = p * 4 + l4;
            int grow = m0 + h * 32 + row;
            if (grow < rows) {
                float4 v = *(const float4*)&TR(wave, row, l15 * 4);
                ushort4 h4, l4v;
                split2(v.x, h4.x, l4v.x);
                split2(v.y, h4.y, l4v.y);
                split2(v.z, h4.z, l4v.z);
                split2(v.w, h4.w, l4v.w);
                size_t off = (size_t)grow * 512 + wcol + l15 * 4;
                *(ushort4*)(es + off) = h4;
                *(ushort4*)(es + off + 256) = l4v;
            }
        }
    }
#undef AH
#undef AL
#undef TR
}

// ------------------------------------------------------------------- GEMM ----
// fp32 row-full GEMM for node convs (N=10k). BN_A: scale/shift inline in
// LDS from stats_in+gamma/beta. DO_STATS: column sum/sumsq into stats_out.
template<bool BN_A, bool ADD_INIT, bool DO_STATS>
__global__ __launch_bounds__(256) void gemm_rowfull(
    const float* A, const float* __restrict__ aggr,
    const float* __restrict__ W, const float* __restrict__ bias,
    const float* __restrict__ stats_in, const float* __restrict__ gamma,
    const float* __restrict__ beta, const float* __restrict__ init,
    float* out, float* __restrict__ stats_out, int rows)
{
    __shared__ float As[16][68];
    __shared__ float Bs[16][260];
    __shared__ float ssc[256], ssf[256];

    const int tid = threadIdx.x;
    const int m0 = blockIdx.x * 64;
    const int tx = tid & 15;
    const int ty = tid >> 4;

    const int arow = tid >> 2;
    const int ak4  = (tid & 3) << 2;
    const int bk   = tid >> 4;
    const int bn4  = (tid & 15) << 2;

    if (BN_A) {
        float inv_n = 1.f / (float)rows;
        float mean = stats_in[tid] * inv_n;
        float var  = stats_in[D + tid] * inv_n - mean * mean;
        float sc = gamma[tid] * rsqrtf(var + BN_EPS);
        ssc[tid] = sc;
        ssf[tid] = beta[tid] - mean * sc;
        __syncthreads();
    }

    float acc[4][16];
#pragma unroll
    for (int i = 0; i < 4; ++i)
#pragma unroll
        for (int j = 0; j < 16; ++j) acc[i][j] = 0.f;

    for (int k0 = 0; k0 < D; k0 += 16) {
        float4 av = make_float4(0.f, 0.f, 0.f, 0.f);
        int gr = m0 + arow;
        if (gr < rows) {
            av = *(const float4*)(A + (size_t)gr * D + k0 + ak4);
            if (BN_A) {
                float4 sc = *(const float4*)&ssc[k0 + ak4];
                float4 sh = *(const float4*)&ssf[k0 + ak4];
                av.x = av.x * sc.x + sh.x;
                av.y = av.y * sc.y + sh.y;
                av.z = av.z * sc.z + sh.z;
                av.w = av.w * sc.w + sh.w;
            }
            float4 g = *(const float4*)(aggr + (size_t)gr * D + k0 + ak4);
            av.x += g.x; av.y += g.y; av.z += g.z; av.w += g.w;
        }
        As[ak4 + 0][arow] = av.x;
        As[ak4 + 1][arow] = av.y;
        As[ak4 + 2][arow] = av.z;
        As[ak4 + 3][arow] = av.w;
#pragma unroll
        for (int c = 0; c < 4; ++c)
            *(float4*)&Bs[bk][c * 64 + bn4] =
                *(const float4*)(W + (size_t)(k0 + bk) * D + c * 64 + bn4);
        __syncthreads();
#pragma unroll
        for (int k = 0; k < 16; ++k) {
            float4 a4 = *(const float4*)&As[k][ty << 2];
            float a[4] = {a4.x, a4.y, a4.z, a4.w};
#pragma unroll
            for (int jc = 0; jc < 4; ++jc) {
                float4 b4 = *(const float4*)&Bs[k][(jc << 6) + (tx << 2)];
#pragma unroll
                for (int i = 0; i < 4; ++i) {
                    acc[i][jc * 4 + 0] += a[i] * b4.x;
                    acc[i][jc * 4 + 1] += a[i] * b4.y;
                    acc[i][jc * 4 + 2] += a[i] * b4.z;
                    acc[i][jc * 4 + 3] += a[i] * b4.w;
                }
            }
        }
        __syncthreads();
    }

    float4 s4[4], q4[4];
#pragma unroll
    for (int jc = 0; jc < 4; ++jc) {
        s4[jc] = make_float4(0.f, 0.f, 0.f, 0.f);
        q4[jc] = make_float4(0.f, 0.f, 0.f, 0.f);
    }
#pragma unroll
    for (int jc = 0; jc < 4; ++jc) {
        int col = (jc << 6) + (tx << 2);
        float4 bias4 = *(const float4*)(bias + col);
#pragma unroll
        for (int i = 0; i < 4; ++i) {
            int gr = m0 + (ty << 2) + i;
            if (gr < rows) {
                float4 o;
                o.x = fmaxf(acc[i][jc * 4 + 0] + bias4.x, 0.f);
                o.y = fmaxf(acc[i][jc * 4 + 1] + bias4.y, 0.f);
                o.z = fmaxf(acc[i][jc * 4 + 2] + bias4.z, 0.f);
                o.w = fmaxf(acc[i][jc * 4 + 3] + bias4.w, 0.f);
                if (ADD_INIT) {
                    float4 iv = *(const float4*)(init + (size_t)gr * D + col);
                    o.x += iv.x; o.y += iv.y; o.z += iv.z; o.w += iv.w;
                }
                if (DO_STATS) {
                    s4[jc].x += o.x; s4[jc].y += o.y;
                    s4[jc].z += o.z; s4[jc].w += o.w;
                    q4[jc].x += o.x * o.x; q4[jc].y += o.y * o.y;
                    q4[jc].z += o.z * o.z; q4[jc].w += o.w * o.w;
                }
                *(float4*)(out + (size_t)gr * D + col) = o;
            }
        }
    }

    if (DO_STATS) {
#pragma unroll
        for (int jc = 0; jc < 4; ++jc)
            *(float4*)&Bs[ty][(jc << 6) + (tx << 2)] = s4[jc];
        __syncthreads();
        {
            float s = 0.f;
#pragma unroll
            for (int t = 0; t < 16; ++t) s += Bs[t][tid];
            atomicAdd(&stats_out[tid], s);
        }
        __syncthreads();
#pragma unroll
        for (int jc = 0; jc < 4; ++jc)
            *(float4*)&Bs[ty][(jc << 6) + (tx << 2)] = q4[jc];
        __syncthreads();
        {
            float s = 0.f;
#pragma unroll
            for (int t = 0; t < 16; ++t) s += Bs[t][tid];
            atomicAdd(&stats_out[D + tid], s);
        }
    }
}

// ----------------------------------------------------------------- launch ----
extern "C" void kernel_launch(void* const* d_in, const int* in_sizes, int n_in,
                              void* d_out, int out_size, void* d_ws, size_t ws_size,
                              hipStream_t stream)
{
    const float* node_feat = (const float*)d_in[0];
    const float* e32       = (const float*)d_in[1];
    const int*   src       = (const int*)d_in[2];
    const int*   dst       = (const int*)d_in[3];
    const float* W_conv    = (const float*)d_in[4];
    const float* b_conv    = (const float*)d_in[5];
    const float* W_edge    = (const float*)d_in[6];
    const float* b_edge    = (const float*)d_in[7];
    const float* gamma     = (const float*)d_in[8];
    const float* beta      = (const float*)d_in[9];
    float*       out       = (float*)d_out;

    const int N = in_sizes[0] / D;
    const int E = in_sizes[2];
    const int L = in_sizes[5] / D;

    float* x          = (float*)d_ws;                  // N*D f32
    float* aggr       = x + (size_t)N * D;             // N*D f32
    float* stats      = aggr + (size_t)N * D;          // L*2*D (slots)
    int*   cnt        = (int*)(stats + (size_t)L * 2 * D); // N
    int*   row_ptr    = cnt + N;                       // N+1
    int*   fillc      = row_ptr + N + 1;               // N
    int*   edge_idx   = fillc + N;                     // E
    int*   src_sorted = edge_idx + E;                  // E
    uintptr_t pa      = ((uintptr_t)(src_sorted + E) + 63) & ~(uintptr_t)63;
    ushort* WTh       = (ushort*)pa;                   // L*D*D bf16 hi
    ushort* WTl       = WTh + (size_t)L * D * D;       // L*D*D bf16 lo
    ushort* es        = WTl + (size_t)L * D * D;       // E*512 (hi|lo rows)

    int nodeBlocks    = (N + 63) / 64;
    int edgeBlocks    = (E + 63) / 64;
    int gatherBlocks  = (N + 3) / 4;
    int eThreadBlocks = (E + 255) / 256;

    // ---- one-time: zero stats slots + CSR + W_edge K-chunk-major hi/lo ----
    hipMemsetAsync(cnt, 0, (size_t)N * sizeof(int), stream);
    hipMemsetAsync(fillc, 0, (size_t)N * sizeof(int), stream);
    hipMemsetAsync(stats, 0, (size_t)L * 2 * D * sizeof(float), stream);
    hist_kernel<<<eThreadBlocks, 256, 0, stream>>>(dst, cnt, E);
    scan_kernel<<<1, 256, 0, stream>>>(cnt, row_ptr, N);
    fill_kernel<<<eThreadBlocks, 256, 0, stream>>>(
        dst, src, row_ptr, fillc, edge_idx, src_sorted, E);
    wconv_kernel<<<L * D, 256, 0, stream>>>(W_edge, WTh, WTl);

    for (int i = 0; i < L; ++i) {
        if (i == 0) {
            gather_l0<<<gatherBlocks, 256, 0, stream>>>(
                node_feat, e32, src, row_ptr, edge_idx, aggr, N);
            gemm_rowfull<false, false, true><<<nodeBlocks, 256, 0, stream>>>(
                node_feat, aggr, W_conv, b_conv, nullptr, nullptr, nullptr,
                nullptr, x, stats, N);
        } else {
            const float* st = stats + (size_t)(i - 1) * 2 * D;
            gather_sorted<<<gatherBlocks, 256, 0, stream>>>(
                x, es, src_sorted, row_ptr, st, gamma + (size_t)(i - 1) * D,
                beta + (size_t)(i - 1) * D, aggr, N);
            gemm_rowfull<true, false, true><<<nodeBlocks, 256, 0, stream>>>(
                x, aggr, W_conv + (size_t)i * D * D, b_conv + (size_t)i * D,
                st, gamma + (size_t)(i - 1) * D, beta + (size_t)(i - 1) * D,
                nullptr, x, stats + (size_t)i * 2 * D, N);
        }
        if (i == 0)
            gemm_edge_mfma<0><<<edgeBlocks, 256, 0, stream>>>(
                e32, edge_idx, nullptr, WTh, WTl, b_edge, es, E);
        else
            gemm_edge_mfma<1><<<edgeBlocks, 256, 0, stream>>>(
                nullptr, nullptr, es, WTh + (size_t)i * D * D,
                WTl + (size_t)i * D * D, b_edge + (size_t)i * D, es, E);
    }

    // final conv: layer L-1 weights on (BN_3(x), gather(es_4)), + node_feat
    {
        const float* st = stats + (size_t)(L - 1) * 2 * D;
        gather_sorted<<<gatherBlocks, 256, 0, stream>>>(
            x, es, src_sorted, row_ptr, st, gamma + (size_t)(L - 1) * D,
            beta + (size_t)(L - 1) * D, aggr, N);
        gemm_rowfull<true, true, false><<<nodeBlocks, 256, 0, stream>>>(
            x, aggr, W_conv + (size_t)(L - 1) * D * D, b_conv + (size_t)(L - 1) * D,
            st, gamma + (size_t)(L - 1) * D, beta + (size_t)(L - 1) * D,
            node_feat, out, nullptr, N);
    }
}

// Round 14
// 1832.726 us; speedup vs baseline: 1.1603x; 1.0004x over previous
//
#include <hip/hip_runtime.h>

// GINEEncoderBlock — round 16: 3-deep A-prefetch in the edge GEMM.
// Calibration from R12/R15: 2-deep coverage = 1 MFMA phase ~470cyc < es
// HBM latency ~900cyc -> ~400cyc stall/K-step (186us vs ~110 pipe-bound);
// 4-deep (R12) = +80 VGPR, crossed the compiler-VGPR 128 band (92->172),
// occupancy halved -> regression. 3-deep = +1 set = +8 VGPR (~100 <= 128,
// same band), coverage = 2 MFMA phases ~940cyc >= HBM latency. Hazard
// discipline identical (set s holds chunk === s mod 3; overwrite only
// after its ds_write, one barrier/step). Everything else = proven R15
// (gathers at floor per R15 null result; co-launch/TLP/4-deep all
// measured regressions; structure frozen).

#define D 256
#define BN_EPS 1e-5f

typedef __attribute__((ext_vector_type(8))) short bf16x8;
typedef __attribute__((ext_vector_type(8))) ushort u16x8;
typedef __attribute__((ext_vector_type(4))) float f32x4;

__device__ __forceinline__ ushort bf16h(float f) {
    uint u = __float_as_uint(f);
    return (ushort)((u + 0x7FFFu + ((u >> 16) & 1u)) >> 16);
}
__device__ __forceinline__ float bf16f(ushort h) {
    return __uint_as_float(((uint)h) << 16);
}

// truncation split: h = top16(f), l = top16(f - h); h+l ~ f to ~2^-16 rel.
__device__ __forceinline__ void split2(float f, ushort& h, ushort& l) {
    uint u = __float_as_uint(f);
    h = (ushort)(u >> 16);
    float r = f - __uint_as_float(u & 0xFFFF0000u);
    l = (ushort)(__float_as_uint(r) >> 16);
}

__device__ __forceinline__ void cvt_write8(const float4& x0, const float4& x1,
                                           ushort* dh, ushort* dl) {
    float f[8] = {x0.x, x0.y, x0.z, x0.w, x1.x, x1.y, x1.z, x1.w};
    u16x8 hv, lv;
#pragma unroll
    for (int j = 0; j < 8; ++j) {
        ushort h, l;
        split2(f[j], h, l);
        hv[j] = h; lv[j] = l;
    }
    *(u16x8*)dh = hv;
    *(u16x8*)dl = lv;
}

// ------------------------------------------------------------- CSR build ----
__global__ __launch_bounds__(256) void hist_kernel(
    const int* __restrict__ dst, int* __restrict__ cnt, int E)
{
    int i = blockIdx.x * 256 + threadIdx.x;
    if (i < E) atomicAdd(&cnt[dst[i]], 1);
}

__global__ __launch_bounds__(256) void scan_kernel(
    const int* __restrict__ cnt, int* __restrict__ row_ptr, int N)
{
    __shared__ int buf[256];
    __shared__ int carry_s;
    if (threadIdx.x == 0) { carry_s = 0; row_ptr[0] = 0; }
    __syncthreads();
    for (int base = 0; base < N; base += 256) {
        int i = base + threadIdx.x;
        int v = (i < N) ? cnt[i] : 0;
        buf[threadIdx.x] = v;
        __syncthreads();
#pragma unroll
        for (int off = 1; off < 256; off <<= 1) {
            int t = (threadIdx.x >= off) ? buf[threadIdx.x - off] : 0;
            __syncthreads();
            buf[threadIdx.x] += t;
            __syncthreads();
        }
        int inc = buf[threadIdx.x] + carry_s;
        if (i < N) row_ptr[i + 1] = inc;
        __syncthreads();
        if (threadIdx.x == 255) carry_s = inc;
        __syncthreads();
    }
}

__global__ __launch_bounds__(256) void fill_kernel(
    const int* __restrict__ dst, const int* __restrict__ src,
    const int* __restrict__ row_ptr, int* __restrict__ fillc,
    int* __restrict__ edge_idx, int* __restrict__ src_sorted, int E)
{
    int i = blockIdx.x * 256 + threadIdx.x;
    if (i < E) {
        int d = dst[i];
        int pos = atomicAdd(&fillc[d], 1);
        int slot = row_ptr[d] + pos;
        edge_idx[slot] = i;
        src_sorted[slot] = src[i];
    }
}

// ------------------------------------------------------- gather (layer 0) ----
__global__ __launch_bounds__(256) void gather_l0(
    const float* __restrict__ x, const float* __restrict__ e32,
    const int* __restrict__ src, const int* __restrict__ row_ptr,
    const int* __restrict__ edge_idx, float* __restrict__ aggr, int N)
{
    int node = blockIdx.x * 4 + (threadIdx.x >> 6);
    if (node >= N) return;
    int lane = threadIdx.x & 63;
    int beg = row_ptr[node], end = row_ptr[node + 1];
    float4 acc = make_float4(0.f, 0.f, 0.f, 0.f);
    if (beg < end) {
        int ed0 = edge_idx[beg];
        int s0  = src[ed0];
        float4 e0 = ((const float4*)(e32 + (size_t)ed0 * D))[lane];
        float4 x0 = ((const float4*)(x + (size_t)s0 * D))[lane];
        for (int j = beg + 1; j < end; ++j) {
            int ed1 = edge_idx[j];
            int s1  = src[ed1];
            float4 e1 = ((const float4*)(e32 + (size_t)ed1 * D))[lane];
            float4 x1 = ((const float4*)(x + (size_t)s1 * D))[lane];
            acc.x += fmaxf(e0.x + x0.x, 0.f);
            acc.y += fmaxf(e0.y + x0.y, 0.f);
            acc.z += fmaxf(e0.z + x0.z, 0.f);
            acc.w += fmaxf(e0.w + x0.w, 0.f);
            e0 = e1; x0 = x1;
        }
        acc.x += fmaxf(e0.x + x0.x, 0.f);
        acc.y += fmaxf(e0.y + x0.y, 0.f);
        acc.z += fmaxf(e0.z + x0.z, 0.f);
        acc.w += fmaxf(e0.w + x0.w, 0.f);
    }
    ((float4*)(aggr + (size_t)node * D))[lane] = acc;
}

// ------------------------------------------------- gather (sorted, BN-x) ----
__global__ __launch_bounds__(256) void gather_sorted(
    const float* __restrict__ x, const ushort* __restrict__ es,
    const int* __restrict__ src_sorted, const int* __restrict__ row_ptr,
    const float* __restrict__ stats, const float* __restrict__ gamma,
    const float* __restrict__ beta, float* __restrict__ aggr, int N)
{
    __shared__ float ssc[256], ssf[256];
    {
        int c = threadIdx.x;
        float inv_n = 1.f / (float)N;
        float mean = stats[c] * inv_n;
        float var  = stats[D + c] * inv_n - mean * mean;
        float sc = gamma[c] * rsqrtf(var + BN_EPS);
        ssc[c] = sc;
        ssf[c] = beta[c] - mean * sc;
    }
    __syncthreads();
    int node = blockIdx.x * 4 + (threadIdx.x >> 6);
    if (node >= N) return;
    int lane = threadIdx.x & 63;
    float4 sc4 = *(const float4*)&ssc[lane * 4];
    float4 sh4 = *(const float4*)&ssf[lane * 4];
    int beg = row_ptr[node], end = row_ptr[node + 1];
    float4 acc = make_float4(0.f, 0.f, 0.f, 0.f);
    if (beg < end) {
        int s0 = src_sorted[beg];
        const ushort* er0 = es + (size_t)beg * 512;
        ushort4 hv0 = *(const ushort4*)(er0 + lane * 4);
        ushort4 lv0 = *(const ushort4*)(er0 + 256 + lane * 4);
        float4  xv0 = ((const float4*)(x + (size_t)s0 * D))[lane];
        for (int j = beg + 1; j < end; ++j) {
            int s1 = src_sorted[j];
            const ushort* er1 = es + (size_t)j * 512;
            ushort4 hv1 = *(const ushort4*)(er1 + lane * 4);
            ushort4 lv1 = *(const ushort4*)(er1 + 256 + lane * 4);
            float4  xv1 = ((const float4*)(x + (size_t)s1 * D))[lane];
            float4 ev;
            ev.x = bf16f(hv0.x) + bf16f(lv0.x);
            ev.y = bf16f(hv0.y) + bf16f(lv0.y);
            ev.z = bf16f(hv0.z) + bf16f(lv0.z);
            ev.w = bf16f(hv0.w) + bf16f(lv0.w);
            acc.x += fmaxf(xv0.x * sc4.x + sh4.x + ev.x, 0.f);
            acc.y += fmaxf(xv0.y * sc4.y + sh4.y + ev.y, 0.f);
            acc.z += fmaxf(xv0.z * sc4.z + sh4.z + ev.z, 0.f);
            acc.w += fmaxf(xv0.w * sc4.w + sh4.w + ev.w, 0.f);
            hv0 = hv1; lv0 = lv1; xv0 = xv1;
        }
        float4 ev;
        ev.x = bf16f(hv0.x) + bf16f(lv0.x);
        ev.y = bf16f(hv0.y) + bf16f(lv0.y);
        ev.z = bf16f(hv0.z) + bf16f(lv0.z);
        ev.w = bf16f(hv0.w) + bf16f(lv0.w);
        acc.x += fmaxf(xv0.x * sc4.x + sh4.x + ev.x, 0.f);
        acc.y += fmaxf(xv0.y * sc4.y + sh4.y + ev.y, 0.f);
        acc.z += fmaxf(xv0.z * sc4.z + sh4.z + ev.z, 0.f);
        acc.w += fmaxf(xv0.w * sc4.w + sh4.w + ev.w, 0.f);
    }
    ((float4*)(aggr + (size_t)node * D))[lane] = acc;
}

// ------------------------------------------- W -> K-chunk-major bf16 hi/lo --
__global__ __launch_bounds__(256) void wconv_kernel(
    const float* __restrict__ W, ushort* __restrict__ WTh,
    ushort* __restrict__ WTl)
{
    int bk = blockIdx.x;            // layer*D + k
    int col = threadIdx.x;
    int layer = bk >> 8, k = bk & 255;
    float v = W[(size_t)bk * D + col];
    ushort h = bf16h(v);
    ushort lo = bf16h(v - bf16f(h));
    size_t o = (((size_t)layer * 8 + (k >> 5)) * 256 + col) * 32 + (k & 31);
    WTh[o] = h;
    WTl[o] = lo;
}

// ----------------------------------------------------- MFMA edge GEMM -------
// R11 structure with A-prefetch deepened 2 -> 3 (sets indexed mod 3).
// 64x256/block, 4 waves, 4x4 16x16x32 frags, hi/lo 3-MFMA; MODE 0 =
// permuted fp32 input (cvt staging), MODE 1 = es linear in-place.
// W 1-deep prefetch; one barrier per K-step; LDS union 34.8KB; epilogue
// Tr transpose -> es row stores [256 hi][256 lo].
template<int MODE>
__global__ __launch_bounds__(256) void gemm_edge_mfma(
    const float* __restrict__ e32, const int* __restrict__ edge_idx,
    const ushort* __restrict__ esin, const ushort* __restrict__ WTh,
    const ushort* __restrict__ WTl, const float* __restrict__ bias,
    ushort* __restrict__ es, int rows)
{
    __shared__ char smem[34816];
    ushort* AhB = (ushort*)smem;              // [2][64][40]
    ushort* AlB = (ushort*)(smem + 10240);    // [2][64][40]
    float*  TrB = (float*)smem;               // [4][32][68] (epilogue reuse)
#define AH(b, r, c) AhB[(b) * 2560 + (r) * 40 + (c)]
#define AL(b, r, c) AlB[(b) * 2560 + (r) * 40 + (c)]
#define TR(w, r, c) TrB[(w) * 2176 + (r) * 68 + (c)]

    const int tid  = threadIdx.x;
    const int lane = tid & 63;
    const int wave = tid >> 6;
    const int m0   = blockIdx.x * 64;
    const int l15  = lane & 15;
    const int l4   = lane >> 4;
    const int wcol = wave * 64;

    const int srow = tid >> 2;    // 0..63
    const int ssec = tid & 3;     // 8-elem sector
    const int sgr  = m0 + srow;
    const bool svalid = (sgr < rows);

    f32x4 acc[4][4];
#pragma unroll
    for (int m = 0; m < 4; ++m)
#pragma unroll
        for (int n = 0; n < 4; ++n) acc[m][n] = (f32x4){0.f, 0.f, 0.f, 0.f};

    float4 pf0[3] = {}, pf1[3] = {};      // MODE0 prefetch sets (3-deep)
    u16x8  ph[3] = {}, pl[3] = {};        // MODE1 prefetch sets (3-deep)
    bf16x8 bh[4], bl[4], bhn[4], bln[4];

    const float*  a32 = nullptr;
    const ushort* ahi = nullptr;
    if (MODE == 0) {
        int erow = svalid ? edge_idx[sgr] : 0;
        a32 = e32 + (size_t)erow * D + ssec * 8;
    } else {
        ahi = esin + (size_t)sgr * 512 + ssec * 8;   // lo at +256
    }

    // ---- prologue: A chunks 0,1,2 -> sets 0,1,2; W chunk 0 -> regs ----
    if (svalid) {
#pragma unroll
        for (int c = 0; c < 3; ++c) {
            if (MODE == 0) {
                const float* p = a32 + c * 32;
                pf0[c] = *(const float4*)p;
                pf1[c] = *(const float4*)(p + 4);
            } else {
                ph[c] = *(const u16x8*)(ahi + c * 32);
                pl[c] = *(const u16x8*)(ahi + 256 + c * 32);
            }
        }
    }
#pragma unroll
    for (int n = 0; n < 4; ++n) {
        size_t o = ((size_t)(wcol + n * 16 + l15)) * 32 + l4 * 8;
        bh[n] = *(const bf16x8*)(WTh + o);
        bl[n] = *(const bf16x8*)(WTl + o);
    }
    if (MODE == 0) {
        cvt_write8(pf0[0], pf1[0], &AH(0, srow, ssec * 8), &AL(0, srow, ssec * 8));
    } else {
        *(u16x8*)&AH(0, srow, ssec * 8) = ph[0];
        *(u16x8*)&AL(0, srow, ssec * 8) = pl[0];
    }
    __syncthreads();

    // ---- K loop: 8 chunks of 32; A 3-deep, W 1-deep prefetch ----
    // set s holds chunk === s (mod 3); chunk kc+3 overwrites the set whose
    // chunk (kc) was ds_written at end of step kc-1 -> safe; the load has
    // 2 full MFMA phases (~940cyc) in flight before its ds_write consumes.
#pragma unroll
    for (int kc = 0; kc < 8; ++kc) {
        const int cur = kc & 1;
        if (kc < 5 && svalid) {            // issue A(kc+3) into set kc%3
            if (MODE == 0) {
                const float* p = a32 + (kc + 3) * 32;
                pf0[kc % 3] = *(const float4*)p;
                pf1[kc % 3] = *(const float4*)(p + 4);
            } else {
                ph[kc % 3] = *(const u16x8*)(ahi + (kc + 3) * 32);
                pl[kc % 3] = *(const u16x8*)(ahi + 256 + (kc + 3) * 32);
            }
        }
        bf16x8 ah[4], al[4];
#pragma unroll
        for (int m = 0; m < 4; ++m) {
            ah[m] = *(const bf16x8*)&AH(cur, m * 16 + l15, l4 * 8);
            al[m] = *(const bf16x8*)&AL(cur, m * 16 + l15, l4 * 8);
        }
        if (kc < 7) {                      // issue W(kc+1)
#pragma unroll
            for (int n = 0; n < 4; ++n) {
                size_t o = ((size_t)(kc + 1) * 256 + wcol + n * 16 + l15) * 32 + l4 * 8;
                bhn[n] = *(const bf16x8*)(WTh + o);
                bln[n] = *(const bf16x8*)(WTl + o);
            }
        }
#pragma unroll
        for (int m = 0; m < 4; ++m)
#pragma unroll
            for (int n = 0; n < 4; ++n) {
                acc[m][n] = __builtin_amdgcn_mfma_f32_16x16x32_bf16(
                    ah[m], bh[n], acc[m][n], 0, 0, 0);
                acc[m][n] = __builtin_amdgcn_mfma_f32_16x16x32_bf16(
                    ah[m], bl[n], acc[m][n], 0, 0, 0);
                acc[m][n] = __builtin_amdgcn_mfma_f32_16x16x32_bf16(
                    al[m], bh[n], acc[m][n], 0, 0, 0);
            }
        if (kc < 7) {                      // stage A(kc+1) from set (kc+1)%3
            const int ns = (kc + 1) % 3;
            if (MODE == 0) {
                cvt_write8(pf0[ns], pf1[ns],
                           &AH(cur ^ 1, srow, ssec * 8), &AL(cur ^ 1, srow, ssec * 8));
            } else {
                *(u16x8*)&AH(cur ^ 1, srow, ssec * 8) = ph[ns];
                *(u16x8*)&AL(cur ^ 1, srow, ssec * 8) = pl[ns];
            }
#pragma unroll
            for (int n = 0; n < 4; ++n) { bh[n] = bhn[n]; bl[n] = bln[n]; }
        }
        __syncthreads();
    }

    // ---- epilogue: bias+relu -> LDS transpose -> es row stores ----
#pragma unroll
    for (int h = 0; h < 2; ++h) {
        __syncthreads();
#pragma unroll
        for (int mm = 0; mm < 2; ++mm) {
            int m = h * 2 + mm;
#pragma unroll
            for (int n = 0; n < 4; ++n) {
                float bv = bias[wcol + n * 16 + l15];
#pragma unroll
                for (int r = 0; r < 4; ++r)
                    TR(wave, mm * 16 + l4 * 4 + r, n * 16 + l15) =
                        fmaxf(acc[m][n][r] + bv, 0.f);
            }
        }
        __syncthreads();
#pragma unroll
        for (int p = 0; p < 8; ++p) {
            int row  = p * 4 + l4;
            int grow = m0 + h * 32 + row;
            if (grow < rows) {
                float4 v = *(const float4*)&TR(wave, row, l15 * 4);
                ushort4 h4, l4v;
                split2(v.x, h4.x, l4v.x);
                split2(v.y, h4.y, l4v.y);
                split2(v.z, h4.z, l4v.z);
                split2(v.w, h4.w, l4v.w);
                size_t off = (size_t)grow * 512 + wcol + l15 * 4;
                *(ushort4*)(es + off) = h4;
                *(ushort4*)(es + off + 256) = l4v;
            }
        }
    }
#undef AH
#undef AL
#undef TR
}

// ------------------------------------------------------------------- GEMM ----
// fp32 row-full GEMM for node convs (N=10k). BN_A: scale/shift inline in
// LDS from stats_in+gamma/beta. DO_STATS: column sum/sumsq into stats_out.
template<bool BN_A, bool ADD_INIT, bool DO_STATS>
__global__ __launch_bounds__(256) void gemm_rowfull(
    const float* A, const float* __restrict__ aggr,
    const float* __restrict__ W, const float* __restrict__ bias,
    const float* __restrict__ stats_in, const float* __restrict__ gamma,
    const float* __restrict__ beta, const float* __restrict__ init,
    float* out, float* __restrict__ stats_out, int rows)
{
    __shared__ float As[16][68];
    __shared__ float Bs[16][260];
    __shared__ float ssc[256], ssf[256];

    const int tid = threadIdx.x;
    const int m0 = blockIdx.x * 64;
    const int tx = tid & 15;
    const int ty = tid >> 4;

    const int arow = tid >> 2;
    const int ak4  = (tid & 3) << 2;
    const int bk   = tid >> 4;
    const int bn4  = (tid & 15) << 2;

    if (BN_A) {
        float inv_n = 1.f / (float)rows;
        float mean = stats_in[tid] * inv_n;
        float var  = stats_in[D + tid] * inv_n - mean * mean;
        float sc = gamma[tid] * rsqrtf(var + BN_EPS);
        ssc[tid] = sc;
        ssf[tid] = beta[tid] - mean * sc;
        __syncthreads();
    }

    float acc[4][16];
#pragma unroll
    for (int i = 0; i < 4; ++i)
#pragma unroll
        for (int j = 0; j < 16; ++j) acc[i][j] = 0.f;

    for (int k0 = 0; k0 < D; k0 += 16) {
        float4 av = make_float4(0.f, 0.f, 0.f, 0.f);
        int gr = m0 + arow;
        if (gr < rows) {
            av = *(const float4*)(A + (size_t)gr * D + k0 + ak4);
            if (BN_A) {
                float4 sc = *(const float4*)&ssc[k0 + ak4];
                float4 sh = *(const float4*)&ssf[k0 + ak4];
                av.x = av.x * sc.x + sh.x;
                av.y = av.y * sc.y + sh.y;
                av.z = av.z * sc.z + sh.z;
                av.w = av.w * sc.w + sh.w;
            }
            float4 g = *(const float4*)(aggr + (size_t)gr * D + k0 + ak4);
            av.x += g.x; av.y += g.y; av.z += g.z; av.w += g.w;
        }
        As[ak4 + 0][arow] = av.x;
        As[ak4 + 1][arow] = av.y;
        As[ak4 + 2][arow] = av.z;
        As[ak4 + 3][arow] = av.w;
#pragma unroll
        for (int c = 0; c < 4; ++c)
            *(float4*)&Bs[bk][c * 64 + bn4] =
                *(const float4*)(W + (size_t)(k0 + bk) * D + c * 64 + bn4);
        __syncthreads();
#pragma unroll
        for (int k = 0; k < 16; ++k) {
            float4 a4 = *(const float4*)&As[k][ty << 2];
            float a[4] = {a4.x, a4.y, a4.z, a4.w};
#pragma unroll
            for (int jc = 0; jc < 4; ++jc) {
                float4 b4 = *(const float4*)&Bs[k][(jc << 6) + (tx << 2)];
#pragma unroll
                for (int i = 0; i < 4; ++i) {
                    acc[i][jc * 4 + 0] += a[i] * b4.x;
                    acc[i][jc * 4 + 1] += a[i] * b4.y;
                    acc[i][jc * 4 + 2] += a[i] * b4.z;
                    acc[i][jc * 4 + 3] += a[i] * b4.w;
                }
            }
        }
        __syncthreads();
    }

    float4 s4[4], q4[4];
#pragma unroll
    for (int jc = 0; jc < 4; ++jc) {
        s4[jc] = make_float4(0.f, 0.f, 0.f, 0.f);
        q4[jc] = make_float4(0.f, 0.f, 0.f, 0.f);
    }
#pragma unroll
    for (int jc = 0; jc < 4; ++jc) {
        int col = (jc << 6) + (tx << 2);
        float4 bias4 = *(const float4*)(bias + col);
#pragma unroll
        for (int i = 0; i < 4; ++i) {
            int gr = m0 + (ty << 2) + i;
            if (gr < rows) {
                float4 o;
                o.x = fmaxf(acc[i][jc * 4 + 0] + bias4.x, 0.f);
                o.y = fmaxf(acc[i][jc * 4 + 1] + bias4.y, 0.f);
                o.z = fmaxf(acc[i][jc * 4 + 2] + bias4.z, 0.f);
                o.w = fmaxf(acc[i][jc * 4 + 3] + bias4.w, 0.f);
                if (ADD_INIT) {
                    float4 iv = *(const float4*)(init + (size_t)gr * D + col);
                    o.x += iv.x; o.y += iv.y; o.z += iv.z; o.w += iv.w;
                }
                if (DO_STATS) {
                    s4[jc].x += o.x; s4[jc].y += o.y;
                    s4[jc].z += o.z; s4[jc].w += o.w;
                    q4[jc].x += o.x * o.x; q4[jc].y += o.y * o.y;
                    q4[jc].z += o.z * o.z; q4[jc].w += o.w * o.w;
                }
                *(float4*)(out + (size_t)gr * D + col) = o;
            }
        }
    }

    if (DO_STATS) {
#pragma unroll
        for (int jc = 0; jc < 4; ++jc)
            *(float4*)&Bs[ty][(jc << 6) + (tx << 2)] = s4[jc];
        __syncthreads();
        {
            float s = 0.f;
#pragma unroll
            for (int t = 0; t < 16; ++t) s += Bs[t][tid];
            atomicAdd(&stats_out[tid], s);
        }
        __syncthreads();
#pragma unroll
        for (int jc = 0; jc < 4; ++jc)
            *(float4*)&Bs[ty][(jc << 6) + (tx << 2)] = q4[jc];
        __syncthreads();
        {
            float s = 0.f;
#pragma unroll
            for (int t = 0; t < 16; ++t) s += Bs[t][tid];
            atomicAdd(&stats_out[D + tid], s);
        }
    }
}

// ----------------------------------------------------------------- launch ----
extern "C" void kernel_launch(void* const* d_in, const int* in_sizes, int n_in,
                              void* d_out, int out_size, void* d_ws, size_t ws_size,
                              hipStream_t stream)
{
    const float* node_feat = (const float*)d_in[0];
    const float* e32       = (const float*)d_in[1];
    const int*   src       = (const int*)d_in[2];
    const int*   dst       = (const int*)d_in[3];
    const float* W_conv    = (const float*)d_in[4];
    const float* b_conv    = (const float*)d_in[5];
    const float* W_edge    = (const float*)d_in[6];
    const float* b_edge    = (const float*)d_in[7];
    const float* gamma     = (const float*)d_in[8];
    const float* beta      = (const float*)d_in[9];
    float*       out       = (float*)d_out;

    const int N = in_sizes[0] / D;
    const int E = in_sizes[2];
    const int L = in_sizes[5] / D;

    float* x          = (float*)d_ws;                  // N*D f32
    float* aggr       = x + (size_t)N * D;             // N*D f32
    float* stats      = aggr + (size_t)N * D;          // L*2*D (slots)
    int*   cnt        = (int*)(stats + (size_t)L * 2 * D); // N
    int*   row_ptr    = cnt + N;                       // N+1
    int*   fillc      = row_ptr + N + 1;               // N
    int*   edge_idx   = fillc + N;                     // E
    int*   src_sorted = edge_idx + E;                  // E
    uintptr_t pa      = ((uintptr_t)(src_sorted + E) + 63) & ~(uintptr_t)63;
    ushort* WTh       = (ushort*)pa;                   // L*D*D bf16 hi
    ushort* WTl       = WTh + (size_t)L * D * D;       // L*D*D bf16 lo
    ushort* es        = WTl + (size_t)L * D * D;       // E*512 (hi|lo rows)

    int nodeBlocks    = (N + 63) / 64;
    int edgeBlocks    = (E + 63) / 64;
    int gatherBlocks  = (N + 3) / 4;
    int eThreadBlocks = (E + 255) / 256;

    // ---- one-time: zero stats slots + CSR + W_edge K-chunk-major hi/lo ----
    hipMemsetAsync(cnt, 0, (size_t)N * sizeof(int), stream);
    hipMemsetAsync(fillc, 0, (size_t)N * sizeof(int), stream);
    hipMemsetAsync(stats, 0, (size_t)L * 2 * D * sizeof(float), stream);
    hist_kernel<<<eThreadBlocks, 256, 0, stream>>>(dst, cnt, E);
    scan_kernel<<<1, 256, 0, stream>>>(cnt, row_ptr, N);
    fill_kernel<<<eThreadBlocks, 256, 0, stream>>>(
        dst, src, row_ptr, fillc, edge_idx, src_sorted, E);
    wconv_kernel<<<L * D, 256, 0, stream>>>(W_edge, WTh, WTl);

    for (int i = 0; i < L; ++i) {
        if (i == 0) {
            gather_l0<<<gatherBlocks, 256, 0, stream>>>(
                node_feat, e32, src, row_ptr, edge_idx, aggr, N);
            gemm_rowfull<false, false, true><<<nodeBlocks, 256, 0, stream>>>(
                node_feat, aggr, W_conv, b_conv, nullptr, nullptr, nullptr,
                nullptr, x, stats, N);
        } else {
            const float* st = stats + (size_t)(i - 1) * 2 * D;
            gather_sorted<<<gatherBlocks, 256, 0, stream>>>(
                x, es, src_sorted, row_ptr, st, gamma + (size_t)(i - 1) * D,
                beta + (size_t)(i - 1) * D, aggr, N);
            gemm_rowfull<true, false, true><<<nodeBlocks, 256, 0, stream>>>(
                x, aggr, W_conv + (size_t)i * D * D, b_conv + (size_t)i * D,
                st, gamma + (size_t)(i - 1) * D, beta + (size_t)(i - 1) * D,
                nullptr, x, stats + (size_t)i * 2 * D, N);
        }
        if (i == 0)
            gemm_edge_mfma<0><<<edgeBlocks, 256, 0, stream>>>(
                e32, edge_idx, nullptr, WTh, WTl, b_edge, es, E);
        else
            gemm_edge_mfma<1><<<edgeBlocks, 256, 0, stream>>>(
                nullptr, nullptr, es, WTh + (size_t)i * D * D,
                WTl + (size_t)i * D * D, b_edge + (size_t)i * D, es, E);
    }

    // final conv: layer L-1 weights on (BN_3(x), gather(es_4)), + node_feat
    {
        const float* st = stats + (size_t)(L - 1) * 2 * D;
        gather_sorted<<<gatherBlocks, 256, 0, stream>>>(
            x, es, src_sorted, row_ptr, st, gamma + (size_t)(L - 1) * D,
            beta + (size_t)(L - 1) * D, aggr, N);
        gemm_rowfull<true, true, false><<<nodeBlocks, 256, 0, stream>>>(
            x, aggr, W_conv + (size_t)(L - 1) * D * D, b_conv + (size_t)(L - 1) * D,
            st, gamma + (size_t)(L - 1) * D, beta + (size_t)(L - 1) * D,
            node_feat, out, nullptr, N);
    }
}